// Round 12
// baseline (448.831 us; speedup 1.0000x reference)
//
#include <hip/hip_runtime.h>

#define N_NODES 50000
#define N_EDGES 800000
#define D_FEAT  128
#define ELL_CAP 64     // slots per node; P(deg>=64)~2e-18 for Poisson(16)
#define NB 64          // scan blocks; each owns RANGE nodes
#define RANGE 784      // 64*784 = 50176 >= N_NODES

typedef unsigned int uint;
typedef unsigned short ushort_t;

union f32u { float f; uint u; };

__device__ __forceinline__ ushort_t f2bf(float f) {
    f32u x; x.f = f;
    uint u = x.u;
    return (ushort_t)((u + 0x7FFFu + ((u >> 16) & 1u)) >> 16);   // RNE
}

// ---------------------------------------------------------------------------
// K1 "ell_build": range-partitioned full scan. Block b owns nodes
// [b*RANGE, (b+1)*RANGE); it streams the ENTIRE src/dst arrays (int4, L2/L3
// resident: 64 x 6.4MB = 410MB aggregate) and slots matching edges into ELL
// using LDS returning atomics (per-node chains ~16 x 40ns, parallel across
// 784 nodes — no global returning atomics anywhere; R10 showed those wall at
// ~19.5G/s, R11 showed same-address chains at ~300ns/op). Emits cnt + norm.
__global__ __launch_bounds__(256) void ell_build(const int4* __restrict__ src4,
                                                 const int4* __restrict__ dst4,
                                                 int* __restrict__ ell,
                                                 int* __restrict__ cnt,
                                                 float* __restrict__ norm) {
    __shared__ int hist[RANGE];
    int lo = blockIdx.x * RANGE;
    for (int i = threadIdx.x; i < RANGE; i += 256) hist[i] = 0;
    __syncthreads();
    for (int i = threadIdx.x; i < N_EDGES / 4; i += 256) {
        int4 d4 = dst4[i];
        int4 s4 = src4[i];
#define DO(c) { int d_ = d4.c; unsigned r_ = (unsigned)(d_ - lo);              \
                if (r_ < RANGE) {                                              \
                    int p_ = atomicAdd(&hist[r_], 1);                          \
                    if (p_ < ELL_CAP) ell[d_ * ELL_CAP + p_] = s4.c;           \
                } }
        DO(x) DO(y) DO(z) DO(w)
#undef DO
    }
    __syncthreads();
    for (int i = threadIdx.x; i < RANGE; i += 256) {
        int n = lo + i;
        if (n < N_NODES) {
            int c = hist[i];
            cnt[n] = c;
            norm[n] = rsqrtf((float)(c < 1 ? 1 : c));
        }
    }
}

// K2 "convert_scale": featb = bf16(feat * norm) in ONE pass (norm is already
// known, unlike R10 where convert ran before the histogram finished and a
// second rescale pass was needed: 64MB -> 38.4MB of streaming traffic).
__global__ void convert_scale(const float4* __restrict__ feat4,
                              const float* __restrict__ norm,
                              ushort4* __restrict__ featb4) {
    int gid = blockIdx.x * 256 + threadIdx.x;
    if (gid < N_NODES * (D_FEAT / 4)) {
        float nn = norm[gid >> 5];           // 32 float4 per node row
        float4 v = feat4[gid];
        ushort4 o;
        o.x = f2bf(v.x * nn); o.y = f2bf(v.y * nn);
        o.z = f2bf(v.z * nn); o.w = f2bf(v.w * nn);
        featb4[gid] = o;
    }
}

// K3: pull-gather hop over PRE-SCALED bf16 rows, ELL edge lists.
// One wave per node, quad-edge layout (lane = 16*q + l16), 16 edges/iter.
//   hop1 (FINAL=0): g1 = sum featb[s];  store s1 = bf16(norm[node]^2 * g1)
//   hop2 (FINAL=1): g2 = sum s1[s];     out = (feat + s1[node]/norm + norm*g2)/3
template<int FINAL>
__global__ void hop_gather(const int* __restrict__ ell, const int* __restrict__ cnt,
                           const ushort_t* __restrict__ hb, const float* __restrict__ norm,
                           const float* __restrict__ feat, const ushort_t* __restrict__ s1,
                           void* __restrict__ outp) {
    int node = blockIdx.x * 4 + (threadIdx.x >> 6);
    int lane = threadIdx.x & 63;
    int q    = lane >> 4;
    int l16  = lane & 15;
    const uint4* hbv = (const uint4*)hb;     // row = 16 uint4 (256B)
    int b    = node * ELL_CAP;
    int ecnt = cnt[node];
    if (ecnt > ELL_CAP) ecnt = ELL_CAP;
    float a0 = 0, a1 = 0, a2 = 0, a3 = 0, a4 = 0, a5 = 0, a6 = 0, a7 = 0;

#define ACC2(P, E_, O_) { f32u lo_, hi_; lo_.u = (P) << 16; hi_.u = (P) & 0xFFFF0000u; \
                          E_ += lo_.f; O_ += hi_.f; }
#define ACCV(V) { ACC2(V.x, a0, a1); ACC2(V.y, a2, a3); ACC2(V.z, a4, a5); ACC2(V.w, a6, a7); }

    int i = 0;
    for (; i + 16 <= ecnt; i += 16) {        // 4 independent row gathers
        int s0 = ell[b + i      + q];
        int s1i = ell[b + i + 4  + q];
        int s2 = ell[b + i + 8  + q];
        int s3 = ell[b + i + 12 + q];
        uint4 v0 = hbv[s0 * 16 + l16];
        uint4 v1 = hbv[s1i * 16 + l16];
        uint4 v2 = hbv[s2 * 16 + l16];
        uint4 v3 = hbv[s3 * 16 + l16];
        ACCV(v0); ACCV(v1); ACCV(v2); ACCV(v3);
    }
    if (i + 8 <= ecnt) {
        int s0 = ell[b + i     + q];
        int s1i = ell[b + i + 4 + q];
        uint4 v0 = hbv[s0 * 16 + l16];
        uint4 v1 = hbv[s1i * 16 + l16];
        ACCV(v0); ACCV(v1);
        i += 8;
    }
    if (i + 4 <= ecnt) {
        int s_ = ell[b + i + q];
        uint4 v_ = hbv[s_ * 16 + l16];
        ACCV(v_);
        i += 4;
    }
    int rem = ecnt - i;                      // 0..3 tail, quarter-predicated
    if (q < rem) {
        int s_ = ell[b + i + q];
        uint4 v_ = hbv[s_ * 16 + l16];
        ACCV(v_);
    }
#undef ACCV
#undef ACC2

    // reduce the 4 quarter-wave partials (same columns, different edges)
    a0 += __shfl_xor(a0, 16, 64); a1 += __shfl_xor(a1, 16, 64);
    a2 += __shfl_xor(a2, 16, 64); a3 += __shfl_xor(a3, 16, 64);
    a4 += __shfl_xor(a4, 16, 64); a5 += __shfl_xor(a5, 16, 64);
    a6 += __shfl_xor(a6, 16, 64); a7 += __shfl_xor(a7, 16, 64);
    a0 += __shfl_xor(a0, 32, 64); a1 += __shfl_xor(a1, 32, 64);
    a2 += __shfl_xor(a2, 32, 64); a3 += __shfl_xor(a3, 32, 64);
    a4 += __shfl_xor(a4, 32, 64); a5 += __shfl_xor(a5, 32, 64);
    a6 += __shfl_xor(a6, 32, 64); a7 += __shfl_xor(a7, 32, 64);

    if (q == 0) {
        float nn = norm[node];
        if (!FINAL) {
            float n2 = nn * nn;              // store norm^2*g1 -> hop2 gathers
            uint4 o;                         //   a pre-scaled operand too
            o.x = (uint)f2bf(a0 * n2) | ((uint)f2bf(a1 * n2) << 16);
            o.y = (uint)f2bf(a2 * n2) | ((uint)f2bf(a3 * n2) << 16);
            o.z = (uint)f2bf(a4 * n2) | ((uint)f2bf(a5 * n2) << 16);
            o.w = (uint)f2bf(a6 * n2) | ((uint)f2bf(a7 * n2) << 16);
            ((uint4*)outp)[node * 16 + l16] = o;
        } else {
            // out = (feat + norm*g1 + norm*g2)/3 ; norm*g1 = s1/norm
            float inv = 1.0f / nn;
            uint4 p = ((const uint4*)s1)[node * 16 + l16];
            f32u t0, t1, t2, t3, t4, t5, t6, t7;
            t0.u = p.x << 16; t1.u = p.x & 0xFFFF0000u;
            t2.u = p.y << 16; t3.u = p.y & 0xFFFF0000u;
            t4.u = p.z << 16; t5.u = p.z & 0xFFFF0000u;
            t6.u = p.w << 16; t7.u = p.w & 0xFFFF0000u;
            const float4* f4 = (const float4*)feat;
            float4 fA = f4[node * 32 + 2 * l16];
            float4 fB = f4[node * 32 + 2 * l16 + 1];
            const float third = 1.0f / 3.0f;
            float4 rA, rB;
            rA.x = (fA.x + t0.f * inv + nn * a0) * third;
            rA.y = (fA.y + t1.f * inv + nn * a1) * third;
            rA.z = (fA.z + t2.f * inv + nn * a2) * third;
            rA.w = (fA.w + t3.f * inv + nn * a3) * third;
            rB.x = (fB.x + t4.f * inv + nn * a4) * third;
            rB.y = (fB.y + t5.f * inv + nn * a5) * third;
            rB.z = (fB.z + t6.f * inv + nn * a6) * third;
            rB.w = (fB.w + t7.f * inv + nn * a7) * third;
            ((float4*)outp)[node * 32 + 2 * l16]     = rA;
            ((float4*)outp)[node * 32 + 2 * l16 + 1] = rB;
        }
    }
}

extern "C" void kernel_launch(void* const* d_in, const int* in_sizes, int n_in,
                              void* d_out, int out_size, void* d_ws, size_t ws_size,
                              hipStream_t stream) {
    const float* feat = (const float*)d_in[0];
    const int*   src  = (const int*)d_in[1];
    const int*   dst  = (const int*)d_in[2];
    float* out = (float*)d_out;

    // workspace layout (~39 MB):
    char* ws = (char*)d_ws;
    int*      cnt   = (int*)     (ws + 0x0000000);  // 50000 i32
    float*    norm  = (float*)   (ws + 0x0040000);  // 50000 f32
    int*      ell   = (int*)     (ws + 0x0080000);  // 50000*64 i32 (12.8 MB)
    ushort_t* featb = (ushort_t*)(ws + 0x0D80000);  // 6.4M bf16 (12.8 MB)
    ushort_t* s1b   = (ushort_t*)(ws + 0x1A80000);  // 6.4M bf16 (12.8 MB)

    ell_build<<<NB, 256, 0, stream>>>((const int4*)src, (const int4*)dst,
                                      ell, cnt, norm);
    convert_scale<<<(N_NODES * (D_FEAT / 4) + 255) / 256, 256, 0, stream>>>(
        (const float4*)feat, norm, (ushort4*)featb);

    hop_gather<0><<<N_NODES / 4, 256, 0, stream>>>(ell, cnt, featb, norm,
                                                   nullptr, nullptr, s1b);
    hop_gather<1><<<N_NODES / 4, 256, 0, stream>>>(ell, cnt, s1b, norm,
                                                   feat, s1b, out);
}

// Round 14
// 105.311 us; speedup vs baseline: 4.2620x; 4.2620x over previous
//
#include <hip/hip_runtime.h>

#define N_NODES 50000
#define N_EDGES 800000
#define D_FEAT  128
#define ELL_CAP 64       // slots per node; P(deg>=64)~2e-18 for Poisson(16)
#define NRANGE  49       // node ranges of 1024 (dst >> 10); 49*1024 = 50176
#define NALIAS  64       // stage aliases per range (chain depth 782/64 ~ 12)
#define ALIAS_MASK 63
#define SCAP    384      // per (range,alias) region; mean 255, +8 sigma
#define NBLK_A  782      // 782*256 int4-threads >= 200000 int4 edges

typedef unsigned int uint;
typedef unsigned short ushort_t;

union f32u { float f; uint u; };

__device__ __forceinline__ ushort_t f2bf(float f) {
    f32u x; x.f = f;
    uint u = x.u;
    return (ushort_t)((u + 0x7FFFu + ((u >> 16) & 1u)) >> 16);   // RNE
}

// ---------------------------------------------------------------------------
// K0: zero gcnt (49*64 = 3136 i32).
__global__ void zero_gcnt(int* __restrict__ gcnt) {
    int i = blockIdx.x * 256 + threadIdx.x;
    if (i < NRANGE * NALIAS) gcnt[i] = 0;
}

// K1 "bucketize": 782 blocks x 1024 edges. Within-block rank via LDS
// range-hist (49 counters); ONE global returning atomic per (block,range)
// present (<=49/block, 38K total ~ 2us at the 19.5G/s wall, chains ~12 deep
// <= R11's 300ns/op limit); staged entries go to contiguous per-(range,alias)
// runs. No same-address hot spots, 782 blocks fill the chip (R12 lesson).
__global__ __launch_bounds__(256) void bucketize(const int4* __restrict__ dst4,
                                                 const int4* __restrict__ src4,
                                                 int* __restrict__ gcnt,
                                                 uint* __restrict__ stage) {
    __shared__ int lcnt[NRANGE];
    __shared__ int lbase[NRANGE];
    int tid = threadIdx.x;
    int g = blockIdx.x;
    for (int i = tid; i < NRANGE; i += 256) lcnt[i] = 0;
    __syncthreads();
    int i4 = g * 256 + tid;
    bool valid = (i4 < N_EDGES / 4);
    int4 d4 = valid ? dst4[i4] : make_int4(0, 0, 0, 0);
    int4 s4 = valid ? src4[i4] : make_int4(0, 0, 0, 0);
    int r0 = 0, r1 = 0, r2 = 0, r3 = 0, k0 = 0, k1 = 0, k2 = 0, k3 = 0;
    if (valid) {
        r0 = d4.x >> 10; k0 = atomicAdd(&lcnt[r0], 1);
        r1 = d4.y >> 10; k1 = atomicAdd(&lcnt[r1], 1);
        r2 = d4.z >> 10; k2 = atomicAdd(&lcnt[r2], 1);
        r3 = d4.w >> 10; k3 = atomicAdd(&lcnt[r3], 1);
    }
    __syncthreads();
    int alias = g & ALIAS_MASK;
    if (tid < NRANGE) {
        int c = lcnt[tid];
        lbase[tid] = c ? atomicAdd(&gcnt[tid * NALIAS + alias], c) : 0;
    }
    __syncthreads();
    if (valid) {
        int b;
        b = lbase[r0] + k0;
        if (b < SCAP) stage[(r0 * NALIAS + alias) * SCAP + b] =
            ((uint)(d4.x & 1023) << 16) | (uint)s4.x;
        b = lbase[r1] + k1;
        if (b < SCAP) stage[(r1 * NALIAS + alias) * SCAP + b] =
            ((uint)(d4.y & 1023) << 16) | (uint)s4.y;
        b = lbase[r2] + k2;
        if (b < SCAP) stage[(r2 * NALIAS + alias) * SCAP + b] =
            ((uint)(d4.z & 1023) << 16) | (uint)s4.z;
        b = lbase[r3] + k3;
        if (b < SCAP) stage[(r3 * NALIAS + alias) * SCAP + b] =
            ((uint)(d4.w & 1023) << 16) | (uint)s4.w;
    }
}

// K2 "rank_build": one block per range (exclusive 1024-node LDS hist).
// Flat index over the range's ~16K staged entries (LDS prefix + binary
// search) keeps all 1024 threads busy; exact ELL slots via LDS returning
// atomics (cheap); emits cnt + norm.
__global__ __launch_bounds__(1024) void rank_build(const int* __restrict__ gcnt,
                                                   const uint* __restrict__ stage,
                                                   int* __restrict__ ell,
                                                   int* __restrict__ cnt,
                                                   float* __restrict__ norm) {
    __shared__ int hist[1024];
    __shared__ int rc[NALIAS];
    __shared__ int pfx[NALIAS + 1];
    int r = blockIdx.x;
    int tid = threadIdx.x;
    hist[tid] = 0;
    if (tid < NALIAS) {
        int n = gcnt[r * NALIAS + tid];
        rc[tid] = n > SCAP ? SCAP : n;
    }
    __syncthreads();
    if (tid == 0) {                          // 64-iter LDS-only scan
        int run = 0;
        for (int a = 0; a < NALIAS; a++) { pfx[a] = run; run += rc[a]; }
        pfx[NALIAS] = run;
    }
    __syncthreads();
    int T = pfx[NALIAS];
    for (int j = tid; j < T; j += 1024) {
        int loa = 0, hia = NALIAS;           // find a: pfx[a] <= j < pfx[a+1]
        while (hia - loa > 1) {
            int mid = (loa + hia) >> 1;
            if (pfx[mid] <= j) loa = mid; else hia = mid;
        }
        uint v = stage[(r * NALIAS + loa) * SCAP + (j - pfx[loa])];
        int ld = v >> 16;
        int s = (int)(v & 0xFFFFu);
        int p = atomicAdd(&hist[ld], 1);     // LDS returning atomic
        if (p < ELL_CAP) ell[(((r << 10) + ld) << 6) + p] = s;
    }
    __syncthreads();
    int node = (r << 10) + tid;
    if (node < N_NODES) {
        int c = hist[tid];
        cnt[node] = c;
        norm[node] = rsqrtf((float)(c < 1 ? 1 : c));
    }
}

// K3 "convert_scale": featb = bf16(feat * norm), single rounding.
__global__ void convert_scale(const float4* __restrict__ feat4,
                              const float* __restrict__ norm,
                              ushort4* __restrict__ featb4) {
    int gid = blockIdx.x * 256 + threadIdx.x;
    if (gid < N_NODES * (D_FEAT / 4)) {
        float nn = norm[gid >> 5];           // 32 float4 per node row
        float4 v = feat4[gid];
        ushort4 o;
        o.x = f2bf(v.x * nn); o.y = f2bf(v.y * nn);
        o.z = f2bf(v.z * nn); o.w = f2bf(v.w * nn);
        featb4[gid] = o;
    }
}

// K4: pull-gather hop over PRE-SCALED bf16 rows, ELL edge lists.
// One wave per node, quad-edge layout (lane = 16*q + l16), 16 edges/iter.
//   hop1 (FINAL=0): g1 = sum featb[s];  store s1 = bf16(norm[node]^2 * g1)
//   hop2 (FINAL=1): g2 = sum s1[s];     out = (feat + s1[node]/norm + norm*g2)/3
template<int FINAL>
__global__ void hop_gather(const int* __restrict__ ell, const int* __restrict__ cnt,
                           const ushort_t* __restrict__ hb, const float* __restrict__ norm,
                           const float* __restrict__ feat, const ushort_t* __restrict__ s1,
                           void* __restrict__ outp) {
    int node = blockIdx.x * 4 + (threadIdx.x >> 6);
    int lane = threadIdx.x & 63;
    int q    = lane >> 4;
    int l16  = lane & 15;
    const uint4* hbv = (const uint4*)hb;     // row = 16 uint4 (256B)
    int b    = node * ELL_CAP;
    int ecnt = cnt[node];
    if (ecnt > ELL_CAP) ecnt = ELL_CAP;
    float a0 = 0, a1 = 0, a2 = 0, a3 = 0, a4 = 0, a5 = 0, a6 = 0, a7 = 0;

#define ACC2(P, E_, O_) { f32u lo_, hi_; lo_.u = (P) << 16; hi_.u = (P) & 0xFFFF0000u; \
                          E_ += lo_.f; O_ += hi_.f; }
#define ACCV(V) { ACC2(V.x, a0, a1); ACC2(V.y, a2, a3); ACC2(V.z, a4, a5); ACC2(V.w, a6, a7); }

    int i = 0;
    for (; i + 16 <= ecnt; i += 16) {        // 4 independent row gathers
        int s0 = ell[b + i      + q];
        int s1i = ell[b + i + 4  + q];
        int s2 = ell[b + i + 8  + q];
        int s3 = ell[b + i + 12 + q];
        uint4 v0 = hbv[s0 * 16 + l16];
        uint4 v1 = hbv[s1i * 16 + l16];
        uint4 v2 = hbv[s2 * 16 + l16];
        uint4 v3 = hbv[s3 * 16 + l16];
        ACCV(v0); ACCV(v1); ACCV(v2); ACCV(v3);
    }
    if (i + 8 <= ecnt) {
        int s0 = ell[b + i     + q];
        int s1i = ell[b + i + 4 + q];
        uint4 v0 = hbv[s0 * 16 + l16];
        uint4 v1 = hbv[s1i * 16 + l16];
        ACCV(v0); ACCV(v1);
        i += 8;
    }
    if (i + 4 <= ecnt) {
        int s_ = ell[b + i + q];
        uint4 v_ = hbv[s_ * 16 + l16];
        ACCV(v_);
        i += 4;
    }
    int rem = ecnt - i;                      // 0..3 tail, quarter-predicated
    if (q < rem) {
        int s_ = ell[b + i + q];
        uint4 v_ = hbv[s_ * 16 + l16];
        ACCV(v_);
    }
#undef ACCV
#undef ACC2

    // reduce the 4 quarter-wave partials (same columns, different edges)
    a0 += __shfl_xor(a0, 16, 64); a1 += __shfl_xor(a1, 16, 64);
    a2 += __shfl_xor(a2, 16, 64); a3 += __shfl_xor(a3, 16, 64);
    a4 += __shfl_xor(a4, 16, 64); a5 += __shfl_xor(a5, 16, 64);
    a6 += __shfl_xor(a6, 16, 64); a7 += __shfl_xor(a7, 16, 64);
    a0 += __shfl_xor(a0, 32, 64); a1 += __shfl_xor(a1, 32, 64);
    a2 += __shfl_xor(a2, 32, 64); a3 += __shfl_xor(a3, 32, 64);
    a4 += __shfl_xor(a4, 32, 64); a5 += __shfl_xor(a5, 32, 64);
    a6 += __shfl_xor(a6, 32, 64); a7 += __shfl_xor(a7, 32, 64);

    if (q == 0) {
        float nn = norm[node];
        if (!FINAL) {
            float n2 = nn * nn;              // store norm^2*g1 -> hop2 gathers
            uint4 o;                         //   a pre-scaled operand too
            o.x = (uint)f2bf(a0 * n2) | ((uint)f2bf(a1 * n2) << 16);
            o.y = (uint)f2bf(a2 * n2) | ((uint)f2bf(a3 * n2) << 16);
            o.z = (uint)f2bf(a4 * n2) | ((uint)f2bf(a5 * n2) << 16);
            o.w = (uint)f2bf(a6 * n2) | ((uint)f2bf(a7 * n2) << 16);
            ((uint4*)outp)[node * 16 + l16] = o;
        } else {
            // out = (feat + norm*g1 + norm*g2)/3 ; norm*g1 = s1/norm
            float inv = 1.0f / nn;
            uint4 p = ((const uint4*)s1)[node * 16 + l16];
            f32u t0, t1, t2, t3, t4, t5, t6, t7;
            t0.u = p.x << 16; t1.u = p.x & 0xFFFF0000u;
            t2.u = p.y << 16; t3.u = p.y & 0xFFFF0000u;
            t4.u = p.z << 16; t5.u = p.z & 0xFFFF0000u;
            t6.u = p.w << 16; t7.u = p.w & 0xFFFF0000u;
            const float4* f4 = (const float4*)feat;
            float4 fA = f4[node * 32 + 2 * l16];
            float4 fB = f4[node * 32 + 2 * l16 + 1];
            const float third = 1.0f / 3.0f;
            float4 rA, rB;
            rA.x = (fA.x + t0.f * inv + nn * a0) * third;
            rA.y = (fA.y + t1.f * inv + nn * a1) * third;
            rA.z = (fA.z + t2.f * inv + nn * a2) * third;
            rA.w = (fA.w + t3.f * inv + nn * a3) * third;
            rB.x = (fB.x + t4.f * inv + nn * a4) * third;
            rB.y = (fB.y + t5.f * inv + nn * a5) * third;
            rB.z = (fB.z + t6.f * inv + nn * a6) * third;
            rB.w = (fB.w + t7.f * inv + nn * a7) * third;
            ((float4*)outp)[node * 32 + 2 * l16]     = rA;
            ((float4*)outp)[node * 32 + 2 * l16 + 1] = rB;
        }
    }
}

extern "C" void kernel_launch(void* const* d_in, const int* in_sizes, int n_in,
                              void* d_out, int out_size, void* d_ws, size_t ws_size,
                              hipStream_t stream) {
    const float* feat = (const float*)d_in[0];
    const int*   src  = (const int*)d_in[1];
    const int*   dst  = (const int*)d_in[2];
    float* out = (float*)d_out;

    // workspace layout (~45 MB), end addresses verified non-overlapping:
    //   gcnt  0x0000000 + 0x3100   -> 0x0003100
    //   cnt   0x0010000 + 0x30D40  -> 0x0040D40
    //   norm  0x0050000 + 0x30D40  -> 0x0080D40
    //   stage 0x0090000 + 0x498000 -> 0x0528000   (R13 BUG: ell was at 0x500000,
    //   ell   0x0530000 + 0xC35000 -> 0x1165000    overlapping stage's tail ->
    //   featb 0x1200000 + 0xC35000 -> 0x1E35000    rank_build clobbered ranges
    //   s1b   0x1F00000 + 0xC35000 -> 0x2B35000    47-48 while reading them)
    char* ws = (char*)d_ws;
    int*      gcnt  = (int*)     (ws + 0x0000000);
    int*      cnt   = (int*)     (ws + 0x0010000);
    float*    norm  = (float*)   (ws + 0x0050000);
    uint*     stage = (uint*)    (ws + 0x0090000);
    int*      ell   = (int*)     (ws + 0x0530000);
    ushort_t* featb = (ushort_t*)(ws + 0x1200000);
    ushort_t* s1b   = (ushort_t*)(ws + 0x1F00000);

    zero_gcnt<<<(NRANGE * NALIAS + 255) / 256, 256, 0, stream>>>(gcnt);
    bucketize<<<NBLK_A, 256, 0, stream>>>((const int4*)dst, (const int4*)src,
                                          gcnt, stage);
    rank_build<<<NRANGE, 1024, 0, stream>>>(gcnt, stage, ell, cnt, norm);
    convert_scale<<<(N_NODES * (D_FEAT / 4) + 255) / 256, 256, 0, stream>>>(
        (const float4*)feat, norm, (ushort4*)featb);

    hop_gather<0><<<N_NODES / 4, 256, 0, stream>>>(ell, cnt, featb, norm,
                                                   nullptr, nullptr, s1b);
    hop_gather<1><<<N_NODES / 4, 256, 0, stream>>>(ell, cnt, s1b, norm,
                                                   feat, s1b, out);
}